// Round 15
// baseline (178.753 us; speedup 1.0000x reference)
//
#include <hip/hip_runtime.h>
#include <hip/hip_bf16.h>

// Problem: B=2, S=2048, D=1024, H=16, dh=64. Inputs fp32, output FP32.
// Round 27 (R26 FAILED numerics -- 3rd strike on q-amortization; direction
// closed per pre-committed falsifier. Reverted attn to R25 exact (best
// passing, 169.7us total)).
//  - GEMM: the K-loop was sync;DMA;sync;compute -- ZERO prefetch, full DMA
//    latency exposed every one of 32 K-steps (the exact R12-attn pathology
//    that R14's pipelined dbuf fixed: 161->72us). Applied the same verified
//    transform: As/Bs double-buffered (16->32KB/block, occupancy caps
//    unchanged: VGPR-bound 4 blk/CU), prologue stage k0=0, loop issues
//    k0+32's DMA into buf^1 BEFORE computing buf, one barrier per step.
//    Lane maps / swizzles / epilogues byte-identical. Explains counters:
//    MfmaUtil 17.7 / VALU 11.5 / HBM 23 = pure latency exposure.
// Carried: R25 attn3 (in-reg P, 2x64 half-tiles/barrier, 8 waves), merged
// prep, XCD-bijective grids, source-side GEMM LDS swizzle, producer
// swizzles, pack2 cvt_pk, setprio, rinv epilogue.

typedef __attribute__((ext_vector_type(8))) short bf16x8;
typedef __attribute__((ext_vector_type(4))) float f32x4;
typedef __attribute__((ext_vector_type(4))) int int4v;

#define MFMA16(A, B, C) __builtin_amdgcn_mfma_f32_16x16x32_bf16((A), (B), (C), 0, 0, 0)

#if __has_builtin(__builtin_amdgcn_exp2f)
#define EXP2(x) __builtin_amdgcn_exp2f(x)
#else
#define EXP2(x) exp2f(x)
#endif

static __device__ __forceinline__ unsigned short f2bf(float f) {
    union { float f; unsigned int u; } v;
    v.f = f;
    unsigned int u = v.u;
    u += ((u >> 16) & 1u) + 0x7FFFu;   // RNE
    return (unsigned short)(u >> 16);
}

// hardware RNE f32->bf16 (compiler emits v_cvt_pk_bf16_f32 for pairs)
static __device__ __forceinline__ unsigned short f2bf_hw(float f) {
    __hip_bfloat16 h = __float2bfloat16(f);
    return *reinterpret_cast<unsigned short*>(&h);
}

// pack two f32 -> one dword of 2 bf16 (lo in [15:0], hi in [31:16]); RNE.
static __device__ __forceinline__ unsigned int pack2(float lo, float hi) {
    unsigned int d;
    asm("v_cvt_pk_bf16_f32 %0, %1, %2" : "=v"(d) : "v"(lo), "v"(hi));
    return d;
}

// async global->LDS DMA, 16B per lane; LDS dest = uniform base + lane*16
static __device__ __forceinline__ void gload_lds16(const void* g, void* l) {
    __builtin_amdgcn_global_load_lds(
        (const __attribute__((address_space(1))) void*)g,
        (__attribute__((address_space(3))) void*)l, 16, 0, 0);
}

// ---------------------------------------------------------------------------
// Pre-pass (merged): blocks [0,2048) cast hs fp32->bf16 (8 elems/thread);
// blocks [2048,2816) transpose+cast W[1024][1024] fp32 -> Wt[n][k] bf16.
// ---------------------------------------------------------------------------
__global__ __launch_bounds__(256) void prep(
    const float* __restrict__ hs,
    const float* __restrict__ W0, const float* __restrict__ W1,
    const float* __restrict__ W2,
    unsigned short* __restrict__ hsb,
    unsigned short* __restrict__ Wt)
{
    __shared__ float Ts[64][65];
    const int bid = blockIdx.x;
    const int t   = threadIdx.x;

    if (bid < 2048) {
        const size_t i = ((size_t)bid * 256 + t) * 8;
        float4 a0 = *reinterpret_cast<const float4*>(hs + i);
        float4 a1 = *reinterpret_cast<const float4*>(hs + i + 4);
        unsigned short tt[8];
        tt[0] = f2bf(a0.x); tt[1] = f2bf(a0.y); tt[2] = f2bf(a0.z); tt[3] = f2bf(a0.w);
        tt[4] = f2bf(a1.x); tt[5] = f2bf(a1.y); tt[6] = f2bf(a1.z); tt[7] = f2bf(a1.w);
        *reinterpret_cast<int4v*>(hsb + i) = *reinterpret_cast<int4v*>(tt);
        return;
    }

    const int l   = bid - 2048;            // 0..767
    const int z   = l >> 8;                // 0..2
    const int rem = l & 255;
    const float* W = (z == 0) ? W0 : (z == 1) ? W1 : W2;
    unsigned short* O = Wt + (size_t)z * 1048576;
    const int n0 = (rem & 15) * 64;
    const int k0 = (rem >> 4) * 64;

    {
        const int kr = t >> 2, nc = (t & 3) * 16;
        const float* p = W + (size_t)(k0 + kr) * 1024 + n0 + nc;
        float4 r0 = *reinterpret_cast<const float4*>(p);
        float4 r1 = *reinterpret_cast<const float4*>(p + 4);
        float4 r2 = *reinterpret_cast<const float4*>(p + 8);
        float4 r3 = *reinterpret_cast<const float4*>(p + 12);
        float* d = &Ts[kr][nc];
        d[0]=r0.x; d[1]=r0.y; d[2]=r0.z; d[3]=r0.w;
        d[4]=r1.x; d[5]=r1.y; d[6]=r1.z; d[7]=r1.w;
        d[8]=r2.x; d[9]=r2.y; d[10]=r2.z; d[11]=r2.w;
        d[12]=r3.x; d[13]=r3.y; d[14]=r3.z; d[15]=r3.w;
    }
    __syncthreads();
    {
        const int nr = t >> 2, kc = (t & 3) * 16;
        unsigned short tmp[16];
#pragma unroll
        for (int i = 0; i < 16; i++) tmp[i] = f2bf(Ts[kc + i][nr]);
        unsigned short* d = O + (size_t)(n0 + nr) * 1024 + k0 + kc;
        *reinterpret_cast<int4v*>(d)     = *reinterpret_cast<int4v*>(&tmp[0]);
        *reinterpret_cast<int4v*>(d + 8) = *reinterpret_cast<int4v*>(&tmp[8]);
    }
}

// ---------------------------------------------------------------------------
// Kernel 3: QKV GEMM (m97 pattern, PIPELINED dbuf DMA staging, 128x128,
// BK=32). Flat grid 768, XCD-bijective; source-side LDS chunk-XOR swizzle.
// K-loop: prologue stages k0=0; each iteration issues k0+32's DMA into the
// other buffer BEFORE computing the current one; single barrier per step
// (its vmcnt drain = prefetch completion) -- the R14-verified transform.
// Epilogues: z=0 Q natural (PRE-SCALED 0.125*log2(e)); z=1 K d-chunk
// swizzle by (s&7); z=2 V^T s-chunk swizzle by (d&7).
// ---------------------------------------------------------------------------
__global__ __launch_bounds__(256) void qkv_gemm_dma(
    const unsigned short* __restrict__ hsb,
    const unsigned short* __restrict__ Wt,
    const float* __restrict__ b0, const float* __restrict__ b1,
    const float* __restrict__ b2,
    unsigned short* __restrict__ Qo,
    unsigned short* __restrict__ Ko,
    unsigned short* __restrict__ Vto)
{
    __shared__ unsigned short As[2][128][32];
    __shared__ unsigned short Bs[2][128][32];

    // XCD-bijective decode
    const int lin  = blockIdx.x;                    // 0..767
    const int pair = (lin & 7) + ((lin >> 6) << 3); // 0..95
    const int z    = pair >> 5;                     // 0..2
    const int m0   = (pair & 31) * 128;
    const int n0   = ((lin >> 3) & 7) * 128;

    const unsigned short* W = Wt + (size_t)z * 1048576;
    const float* bias = (z == 0) ? b0 : (z == 1) ? b1 : b2;

    const int tid  = threadIdx.x;
    const int lane = tid & 63;
    const int w    = tid >> 6;
    const int l15  = lane & 15;
    const int quad = lane >> 4;
    const int wm   = (w >> 1) * 64;
    const int wn   = (w & 1) * 64;

    const int drow = lane >> 2;                         // 0..15
    const int dcol = (((lane & 3) ^ ((drow ^ (drow >> 2)) & 3)) * 8);
    const int cfr  = ((quad ^ ((l15 ^ (l15 >> 2)) & 3)) & 3) * 8;

    f32x4 acc[4][4];
#pragma unroll
    for (int i = 0; i < 4; i++)
#pragma unroll
        for (int j = 0; j < 4; j++)
            acc[i][j] = (f32x4){0.f, 0.f, 0.f, 0.f};

    // prologue: stage k0=0 into buffer 0
#pragma unroll
    for (int p = 0; p < 2; p++) {
        const int s = w * 2 + p;
        gload_lds16(hsb + (size_t)(m0 + s * 16 + drow) * 1024 + dcol,
                    &As[0][s * 16][0]);
        gload_lds16(W   + (size_t)(n0 + s * 16 + drow) * 1024 + dcol,
                    &Bs[0][s * 16][0]);
    }
    __syncthreads();

    int cur = 0;
    for (int k0 = 0; k0 < 1024; k0 += 32) {
        // issue next K-step's DMA into the other buffer; it drains at the
        // end-of-iteration barrier, i.e. after a full compute phase.
        if (k0 < 992) {
            const int kn = k0 + 32;
#pragma unroll
            for (int p = 0; p < 2; p++) {
                const int s = w * 2 + p;
                gload_lds16(hsb + (size_t)(m0 + s * 16 + drow) * 1024 + kn + dcol,
                            &As[cur ^ 1][s * 16][0]);
                gload_lds16(W   + (size_t)(n0 + s * 16 + drow) * 1024 + kn + dcol,
                            &Bs[cur ^ 1][s * 16][0]);
            }
        }

        bf16x8 af[4], bfr[4];
#pragma unroll
        for (int i = 0; i < 4; i++)
            af[i] = *reinterpret_cast<const bf16x8*>(&As[cur][wm + i * 16 + l15][cfr]);
#pragma unroll
        for (int j = 0; j < 4; j++)
            bfr[j] = *reinterpret_cast<const bf16x8*>(&Bs[cur][wn + j * 16 + l15][cfr]);
#pragma unroll
        for (int i = 0; i < 4; i++)
#pragma unroll
            for (int j = 0; j < 4; j++)
                acc[i][j] = MFMA16(af[i], bfr[j], acc[i][j]);

        __syncthreads();   // drains next K-step's DMA + guards buffer reuse
        cur ^= 1;
    }

    if (z == 0) {
        // Q: natural [B,H,S,dh], pre-scaled by 0.125*log2(e)
        const float qs = 0.18033688f;
#pragma unroll
        for (int i = 0; i < 4; i++) {
            const int mbase = m0 + wm + i * 16 + quad * 4;
#pragma unroll
            for (int j = 0; j < 4; j++) {
                const int n = n0 + wn + j * 16 + l15;
                const int h = n >> 6, d = n & 63;
                const float bn = bias[n];
#pragma unroll
                for (int r = 0; r < 4; r++) {
                    const int mm = mbase + r;
                    const int b = mm >> 11, s = mm & 2047;
                    Qo[(((size_t)(b * 16 + h) * 2048 + s) * 64) + d] =
                        f2bf((acc[i][j][r] + bn) * qs);
                }
            }
        }
    } else if (z == 1) {
        // K: [B,H,S,dh] with d-chunk swizzle by (s&7)
#pragma unroll
        for (int i = 0; i < 4; i++) {
            const int mbase = m0 + wm + i * 16 + quad * 4;
#pragma unroll
            for (int j = 0; j < 4; j++) {
                const int n = n0 + wn + j * 16 + l15;
                const int h = n >> 6, d = n & 63;
                const float bn = bias[n];
#pragma unroll
                for (int r = 0; r < 4; r++) {
                    const int mm = mbase + r;
                    const int b = mm >> 11, s = mm & 2047;
                    const int dsw = ((((d >> 3) ^ (s & 7)) & 7) << 3) | (d & 7);
                    Ko[(((size_t)(b * 16 + h) * 2048 + s) * 64) + dsw] =
                        f2bf(acc[i][j][r] + bn);
                }
            }
        }
    } else {
        // V^T: [B,H,dh,S] with s-chunk swizzle by (d&7); 4 consecutive s packed
#pragma unroll
        for (int i = 0; i < 4; i++) {
            const int mbase = m0 + wm + i * 16 + quad * 4;
            const int b = mbase >> 11, s0 = mbase & 2047;
#pragma unroll
            for (int j = 0; j < 4; j++) {
                const int n = n0 + wn + j * 16 + l15;
                const int h = n >> 6, d = n & 63;
                const float bn = bias[n];
                ushort4 v4;
                v4.x = f2bf(acc[i][j][0] + bn);
                v4.y = f2bf(acc[i][j][1] + bn);
                v4.z = f2bf(acc[i][j][2] + bn);
                v4.w = f2bf(acc[i][j][3] + bn);
                const int cs  = (s0 & 63) >> 3;
                const int ssw = (s0 & ~63) | (((cs ^ (d & 7)) & 7) << 3) | (s0 & 7);
                *reinterpret_cast<ushort4*>(
                    Vto + ((size_t)(b * 16 + h) * 64 + d) * 2048 + ssw) = v4;
            }
        }
    }
}

// ---------------------------------------------------------------------------
// Kernel 4: MFMA flash attention, max-free softmax, in-register P.
// 1 block = (b,h,128 q-rows), 8 waves; wave w owns q-rows [16w,16w+16).
// KVBLK=128 as 2x64 half-tiles per barrier: each half uses the verified
// 64x64 LDS layout + compute body; 16 iterations, barriers halved.
// Swapped QK^T -> in-register P; cvt_pk + permlane redistribution.
// Flat grid 512, XCD-bijective (K/V L2-resident). (R25 exact.)
// ---------------------------------------------------------------------------
__global__ __launch_bounds__(512) void attn3(
    const unsigned short* __restrict__ Qg,
    const unsigned short* __restrict__ Kg,
    const unsigned short* __restrict__ Vtg,
    float* __restrict__ out)
{
    __shared__ unsigned short Ks[2][2][64][64];   // [buf][half][kk][d] swizzled
    __shared__ unsigned short Vs[2][2][64][64];   // [buf][half][d][kk] swizzled

    const int tid  = threadIdx.x;
    const int lane = tid & 63;
    const int w    = tid >> 6;        // 0..7
    const int l15  = lane & 15;
    const int quad = lane >> 4;

    // XCD-bijective decode: lin = (bh&7) + 8*qb + 128*(bh>>3)
    const int lin = blockIdx.x;               // 0..511
    const int qb  = (lin >> 3) & 15;
    const int bh  = (lin & 7) | ((lin >> 7) << 3);
    const int q0  = qb * 128;
    const size_t base = (size_t)bh * 2048 * 64;
    const unsigned short* Qh  = Qg  + base;
    const unsigned short* Kh  = Kg  + base;
    const unsigned short* Vth = Vtg + base;
    const int b = bh >> 4;
    const int h = bh & 15;

    const int drow = lane >> 3;       // 0..7
    const int dcol = (lane & 7) * 8;  // 0..56

    bf16x8 qf[2];
#pragma unroll
    for (int ks = 0; ks < 2; ks++)
        qf[ks] = *reinterpret_cast<const bf16x8*>(
            Qh + (size_t)(q0 + w * 16 + l15) * 64 + ks * 32 + quad * 8);

    f32x4 o[4];
#pragma unroll
    for (int t = 0; t < 4; t++) o[t] = (f32x4){0.f, 0.f, 0.f, 0.f};
    float rsum = 0.f;   // per-lane: q = w*16 + l15

    // swizzled chunk columns for frag reads (row&7 == l15&7 for 16-row tiles)
    const int c0 = (((quad + 0) ^ (l15 & 7)) & 7) * 8;
    const int c1 = (((quad + 4) ^ (l15 & 7)) & 7) * 8;

    // prologue: stage tile 0, both halves (each wave: 8 K-rows, 8 V-rows per half)
#pragma unroll
    for (int hh = 0; hh < 2; hh++) {
        gload_lds16(Kh  + (size_t)(hh * 64 + w * 8 + drow) * 64 + dcol,
                    &Ks[0][hh][w * 8][0]);
        gload_lds16(Vth + (size_t)(w * 8 + drow) * 2048 + hh * 64 + dcol,
                    &Vs[0][hh][w * 8][0]);
    }
    __syncthreads();

    int cur = 0;
    for (int kt = 0; kt < 16; kt++) {
        // prefetch next 128-k tile (both halves) into the other buffer
        if (kt < 15) {
            const int kn = kt + 1;
#pragma unroll
            for (int hh = 0; hh < 2; hh++) {
                gload_lds16(Kh  + (size_t)(kn * 128 + hh * 64 + w * 8 + drow) * 64 + dcol,
                            &Ks[cur ^ 1][hh][w * 8][0]);
                gload_lds16(Vth + (size_t)(w * 8 + drow) * 2048 + kn * 128 + hh * 64 + dcol,
                            &Vs[cur ^ 1][hh][w * 8][0]);
            }
        }

#pragma unroll
        for (int hh = 0; hh < 2; hh++) {
            const unsigned short (*Kc)[64] = Ks[cur][hh];
            const unsigned short (*Vc)[64] = Vs[cur][hh];

            // S^T = K Q^T (swapped operands; scale+ln2 folded into Q).
            unsigned int D[4][2];
#pragma unroll
            for (int t = 0; t < 4; t++) {
                f32x4 sc = (f32x4){0.f, 0.f, 0.f, 0.f};
                bf16x8 kf0 = *reinterpret_cast<const bf16x8*>(&Kc[t * 16 + l15][c0]);
                bf16x8 kf1 = *reinterpret_cast<const bf16x8*>(&Kc[t * 16 + l15][c1]);
                __builtin_amdgcn_s_setprio(1);
                sc = MFMA16(kf0, qf[0], sc);
                sc = MFMA16(kf1, qf[1], sc);
                __builtin_amdgcn_s_setprio(0);
                const float p0 = EXP2(sc[0]);
                const float p1 = EXP2(sc[1]);
                const float p2 = EXP2(sc[2]);
                const float p3 = EXP2(sc[3]);
                rsum += (p0 + p1) + (p2 + p3);
                D[t][0] = pack2(p0, p1);
                D[t][1] = pack2(p2, p3);
            }

            // redistribute to PV A-fragment layout via permlane swaps
            bf16x8 pf[2];
#pragma unroll
            for (int ks = 0; ks < 2; ks++) {
                unsigned int x0 = D[2 * ks][0], y0 = D[2 * ks + 1][0];
                unsigned int x1 = D[2 * ks][1], y1 = D[2 * ks + 1][1];
                asm("v_permlane32_swap_b32 %0, %1" : "+v"(x0), "+v"(y0));
                asm("v_permlane16_swap_b32 %0, %1" : "+v"(x0), "+v"(y0));
                asm("v_permlane32_swap_b32 %0, %1" : "+v"(x1), "+v"(y1));
                asm("v_permlane16_swap_b32 %0, %1" : "+v"(x1), "+v"(y1));
                int4v pv_;
                pv_.x = (int)x0; pv_.y = (int)x1; pv_.z = (int)y0; pv_.w = (int)y1;
                pf[ks] = *reinterpret_cast<bf16x8*>(&pv_);
            }

#pragma unroll
            for (int t = 0; t < 4; t++) {
                bf16x8 vf0 = *reinterpret_cast<const bf16x8*>(&Vc[t * 16 + l15][c0]);
                bf16x8 vf1 = *reinterpret_cast<const bf16x8*>(&Vc[t * 16 + l15][c1]);
                __builtin_amdgcn_s_setprio(1);
                o[t] = MFMA16(pf[0], vf0, o[t]);
                o[t] = MFMA16(pf[1], vf1, o[t]);
                __builtin_amdgcn_s_setprio(0);
            }
        }

        __syncthreads();   // drains next tile's DMA + guards buffer reuse
        cur ^= 1;
    }

    // rsum total for q=w*16+l15: sum the 4 quads' partials
    rsum += __shfl_xor(rsum, 16, 64);
    rsum += __shfl_xor(rsum, 32, 64);
    float rinv[4];
#pragma unroll
    for (int r = 0; r < 4; r++)
        rinv[r] = 1.0f / __shfl(rsum, quad * 4 + r, 64);

    // epilogue: out[b][q][h*64+d], fp32
#pragma unroll
    for (int t = 0; t < 4; t++) {
#pragma unroll
        for (int r = 0; r < 4; r++) {
            const int q = q0 + w * 16 + quad * 4 + r;
            const size_t oidx = (((size_t)b * 2048 + q) * 16 + h) * 64 + t * 16 + l15;
            out[oidx] = o[t][r] * rinv[r];
        }
    }
}

// ---------------------------------------------------------------------------
__global__ void fill_sentinel(float* out, int n, float pat) {
    int i = blockIdx.x * blockDim.x + threadIdx.x;
    if (i < n) out[i] = pat;
}

// ---------------------------------------------------------------------------
extern "C" void kernel_launch(void* const* d_in, const int* in_sizes, int n_in,
                              void* d_out, int out_size, void* d_ws, size_t ws_size,
                              hipStream_t stream) {
    const size_t n_hs  = (size_t)4096 * 1024;
    const size_t n_w   = (size_t)1024 * 1024;
    const size_t n_qkv = n_hs;
    const size_t need = (n_hs + 3 * n_w + 3 * n_qkv) * sizeof(unsigned short);

    bool order_ok = (n_in == 7) &&
        in_sizes[0] == 4194304 &&
        in_sizes[1] == 1048576 && in_sizes[2] == 1024 &&
        in_sizes[3] == 1048576 && in_sizes[4] == 1024 &&
        in_sizes[5] == 1048576 && in_sizes[6] == 1024;
    if (!order_ok || out_size != 4194304) {
        fill_sentinel<<<(out_size + 255) / 256, 256, 0, stream>>>(
            (float*)d_out, out_size, 4.0f);
        return;
    }
    if (ws_size < need) {
        fill_sentinel<<<(out_size + 255) / 256, 256, 0, stream>>>(
            (float*)d_out, out_size, 2.0f);
        return;
    }

    const float* hs = (const float*)d_in[0];
    const float* Wq = (const float*)d_in[1];
    const float* bq = (const float*)d_in[2];
    const float* Wk = (const float*)d_in[3];
    const float* bk = (const float*)d_in[4];
    const float* Wv = (const float*)d_in[5];
    const float* bv = (const float*)d_in[6];

    unsigned short* hsb = (unsigned short*)d_ws;
    unsigned short* Wt  = hsb + n_hs;
    unsigned short* Q   = Wt + 3 * n_w;
    unsigned short* K   = Q + n_qkv;
    unsigned short* Vt  = K + n_qkv;

    prep<<<2816, 256, 0, stream>>>(hs, Wq, Wk, Wv, hsb, Wt);

    qkv_gemm_dma<<<dim3(768), dim3(256), 0, stream>>>(hsb, Wt, bq, bk, bv, Q, K, Vt);

    attn3<<<dim3(512), dim3(512), 0, stream>>>(Q, K, Vt, (float*)d_out);
}

// Round 16
// 168.920 us; speedup vs baseline: 1.0582x; 1.0582x over previous
//
#include <hip/hip_runtime.h>
#include <hip/hip_bf16.h>

// Problem: B=2, S=2048, D=1024, H=16, dh=64. Inputs fp32, output FP32.
// Round 28 (R27 REGRESSED: dbuf-GEMM 49->56us -- single-barrier prefetch
// must drain within one 16-MFMA phase; reverted to 2-barrier. Conflict
// counter identical pre/post cfr-swizzle (3145728) -> that swizzle was
// inert; removed).
//  - GEMM BK=32 -> 64 = m97's PROVEN 874-TF structure (128^2 tile, width-16
//    DMA, 2 barriers/K-step, 16 steps). R15's BK=64 failure explained: its
//    64-col rows (128B = 0 mod 32 banks) + unswizzled frag reads = 16-way
//    conflict. Fixed with attn3's 8-chunk XOR (c0/c1, ~12 rounds proven on
//    identical 64-col tiles): phys chunk = logical ^ (row&7), applied
//    source-side at DMA (m173). Frag banks now 2-way (free, m136).
//  - attn3 + prep = R25-exact (best passing attn).
// Carried: XCD-bijective grids, producer K/V^T swizzles, in-reg-P attn,
// pack2 cvt_pk, setprio, rinv epilogue, merged prep.

typedef __attribute__((ext_vector_type(8))) short bf16x8;
typedef __attribute__((ext_vector_type(4))) float f32x4;
typedef __attribute__((ext_vector_type(4))) int int4v;

#define MFMA16(A, B, C) __builtin_amdgcn_mfma_f32_16x16x32_bf16((A), (B), (C), 0, 0, 0)

#if __has_builtin(__builtin_amdgcn_exp2f)
#define EXP2(x) __builtin_amdgcn_exp2f(x)
#else
#define EXP2(x) exp2f(x)
#endif

static __device__ __forceinline__ unsigned short f2bf(float f) {
    union { float f; unsigned int u; } v;
    v.f = f;
    unsigned int u = v.u;
    u += ((u >> 16) & 1u) + 0x7FFFu;   // RNE
    return (unsigned short)(u >> 16);
}

// hardware RNE f32->bf16 (compiler emits v_cvt_pk_bf16_f32 for pairs)
static __device__ __forceinline__ unsigned short f2bf_hw(float f) {
    __hip_bfloat16 h = __float2bfloat16(f);
    return *reinterpret_cast<unsigned short*>(&h);
}

// pack two f32 -> one dword of 2 bf16 (lo in [15:0], hi in [31:16]); RNE.
static __device__ __forceinline__ unsigned int pack2(float lo, float hi) {
    unsigned int d;
    asm("v_cvt_pk_bf16_f32 %0, %1, %2" : "=v"(d) : "v"(lo), "v"(hi));
    return d;
}

// async global->LDS DMA, 16B per lane; LDS dest = uniform base + lane*16
static __device__ __forceinline__ void gload_lds16(const void* g, void* l) {
    __builtin_amdgcn_global_load_lds(
        (const __attribute__((address_space(1))) void*)g,
        (__attribute__((address_space(3))) void*)l, 16, 0, 0);
}

// ---------------------------------------------------------------------------
// Pre-pass (merged): blocks [0,2048) cast hs fp32->bf16 (8 elems/thread);
// blocks [2048,2816) transpose+cast W[1024][1024] fp32 -> Wt[n][k] bf16.
// ---------------------------------------------------------------------------
__global__ __launch_bounds__(256) void prep(
    const float* __restrict__ hs,
    const float* __restrict__ W0, const float* __restrict__ W1,
    const float* __restrict__ W2,
    unsigned short* __restrict__ hsb,
    unsigned short* __restrict__ Wt)
{
    __shared__ float Ts[64][65];
    const int bid = blockIdx.x;
    const int t   = threadIdx.x;

    if (bid < 2048) {
        const size_t i = ((size_t)bid * 256 + t) * 8;
        float4 a0 = *reinterpret_cast<const float4*>(hs + i);
        float4 a1 = *reinterpret_cast<const float4*>(hs + i + 4);
        unsigned short tt[8];
        tt[0] = f2bf(a0.x); tt[1] = f2bf(a0.y); tt[2] = f2bf(a0.z); tt[3] = f2bf(a0.w);
        tt[4] = f2bf(a1.x); tt[5] = f2bf(a1.y); tt[6] = f2bf(a1.z); tt[7] = f2bf(a1.w);
        *reinterpret_cast<int4v*>(hsb + i) = *reinterpret_cast<int4v*>(tt);
        return;
    }

    const int l   = bid - 2048;            // 0..767
    const int z   = l >> 8;                // 0..2
    const int rem = l & 255;
    const float* W = (z == 0) ? W0 : (z == 1) ? W1 : W2;
    unsigned short* O = Wt + (size_t)z * 1048576;
    const int n0 = (rem & 15) * 64;
    const int k0 = (rem >> 4) * 64;

    {
        const int kr = t >> 2, nc = (t & 3) * 16;
        const float* p = W + (size_t)(k0 + kr) * 1024 + n0 + nc;
        float4 r0 = *reinterpret_cast<const float4*>(p);
        float4 r1 = *reinterpret_cast<const float4*>(p + 4);
        float4 r2 = *reinterpret_cast<const float4*>(p + 8);
        float4 r3 = *reinterpret_cast<const float4*>(p + 12);
        float* d = &Ts[kr][nc];
        d[0]=r0.x; d[1]=r0.y; d[2]=r0.z; d[3]=r0.w;
        d[4]=r1.x; d[5]=r1.y; d[6]=r1.z; d[7]=r1.w;
        d[8]=r2.x; d[9]=r2.y; d[10]=r2.z; d[11]=r2.w;
        d[12]=r3.x; d[13]=r3.y; d[14]=r3.z; d[15]=r3.w;
    }
    __syncthreads();
    {
        const int nr = t >> 2, kc = (t & 3) * 16;
        unsigned short tmp[16];
#pragma unroll
        for (int i = 0; i < 16; i++) tmp[i] = f2bf(Ts[kc + i][nr]);
        unsigned short* d = O + (size_t)(n0 + nr) * 1024 + k0 + kc;
        *reinterpret_cast<int4v*>(d)     = *reinterpret_cast<int4v*>(&tmp[0]);
        *reinterpret_cast<int4v*>(d + 8) = *reinterpret_cast<int4v*>(&tmp[8]);
    }
}

// ---------------------------------------------------------------------------
// Kernel 3: QKV GEMM -- m97 structure: 128x128 tile, BK=64, width-16 DMA,
// 2 barriers per K-step, 16 K-steps. Flat grid 768, XCD-bijective.
// LDS tiles [128][64] with 8-chunk XOR swizzle (phys = logical ^ (row&7)),
// applied source-side at DMA; frag reads use attn-proven c0/c1 formula.
// Epilogues: z=0 Q natural (PRE-SCALED 0.125*log2(e)); z=1 K d-chunk
// swizzle by (s&7); z=2 V^T s-chunk swizzle by (d&7).
// ---------------------------------------------------------------------------
__global__ __launch_bounds__(256) void qkv_gemm_dma(
    const unsigned short* __restrict__ hsb,
    const unsigned short* __restrict__ Wt,
    const float* __restrict__ b0, const float* __restrict__ b1,
    const float* __restrict__ b2,
    unsigned short* __restrict__ Qo,
    unsigned short* __restrict__ Ko,
    unsigned short* __restrict__ Vto)
{
    __shared__ unsigned short As[128][64];
    __shared__ unsigned short Bs[128][64];

    // XCD-bijective decode
    const int lin  = blockIdx.x;                    // 0..767
    const int pair = (lin & 7) + ((lin >> 6) << 3); // 0..95
    const int z    = pair >> 5;                     // 0..2
    const int m0   = (pair & 31) * 128;
    const int n0   = ((lin >> 3) & 7) * 128;

    const unsigned short* W = Wt + (size_t)z * 1048576;
    const float* bias = (z == 0) ? b0 : (z == 1) ? b1 : b2;

    const int tid  = threadIdx.x;
    const int lane = tid & 63;
    const int w    = tid >> 6;
    const int l15  = lane & 15;
    const int quad = lane >> 4;
    const int wm   = (w >> 1) * 64;
    const int wn   = (w & 1) * 64;

    // staging: each DMA covers 8 rows x 64 cols; lane -> row s+(lane>>3),
    // phys chunk lane&7. Source col = (phys ^ (row&7))*8 = ((lane&7)^(lane>>3))*8
    const int drow8 = lane >> 3;                       // 0..7 == row&7
    const int scol  = ((lane & 7) ^ drow8) * 8;        // source-side XOR

    // frag-read cols (attn-proven): logical chunk kk*4+quad at row&7==l15&7
    const int c0 = (((quad + 0) ^ (l15 & 7)) & 7) * 8;   // kk=0
    const int c1 = (((quad + 4) ^ (l15 & 7)) & 7) * 8;   // kk=1

    f32x4 acc[4][4];
#pragma unroll
    for (int i = 0; i < 4; i++)
#pragma unroll
        for (int j = 0; j < 4; j++)
            acc[i][j] = (f32x4){0.f, 0.f, 0.f, 0.f};

    for (int k0 = 0; k0 < 1024; k0 += 64) {
        __syncthreads();
#pragma unroll
        for (int p = 0; p < 4; p++) {
            const int s = w * 32 + p * 8;   // wave w stages rows [32w,32w+32)
            gload_lds16(hsb + (size_t)(m0 + s + drow8) * 1024 + k0 + scol,
                        &As[s][0]);
            gload_lds16(W   + (size_t)(n0 + s + drow8) * 1024 + k0 + scol,
                        &Bs[s][0]);
        }
        __syncthreads();

#pragma unroll
        for (int kk = 0; kk < 2; kk++) {
            const int cc = (kk == 0) ? c0 : c1;
            bf16x8 af[4], bfr[4];
#pragma unroll
            for (int i = 0; i < 4; i++)
                af[i] = *reinterpret_cast<const bf16x8*>(
                    &As[wm + i * 16 + l15][cc]);
#pragma unroll
            for (int j = 0; j < 4; j++)
                bfr[j] = *reinterpret_cast<const bf16x8*>(
                    &Bs[wn + j * 16 + l15][cc]);
#pragma unroll
            for (int i = 0; i < 4; i++)
#pragma unroll
                for (int j = 0; j < 4; j++)
                    acc[i][j] = MFMA16(af[i], bfr[j], acc[i][j]);
        }
    }

    if (z == 0) {
        // Q: natural [B,H,S,dh], pre-scaled by 0.125*log2(e)
        const float qs = 0.18033688f;
#pragma unroll
        for (int i = 0; i < 4; i++) {
            const int mbase = m0 + wm + i * 16 + quad * 4;
#pragma unroll
            for (int j = 0; j < 4; j++) {
                const int n = n0 + wn + j * 16 + l15;
                const int h = n >> 6, d = n & 63;
                const float bn = bias[n];
#pragma unroll
                for (int r = 0; r < 4; r++) {
                    const int mm = mbase + r;
                    const int b = mm >> 11, s = mm & 2047;
                    Qo[(((size_t)(b * 16 + h) * 2048 + s) * 64) + d] =
                        f2bf((acc[i][j][r] + bn) * qs);
                }
            }
        }
    } else if (z == 1) {
        // K: [B,H,S,dh] with d-chunk swizzle by (s&7)
#pragma unroll
        for (int i = 0; i < 4; i++) {
            const int mbase = m0 + wm + i * 16 + quad * 4;
#pragma unroll
            for (int j = 0; j < 4; j++) {
                const int n = n0 + wn + j * 16 + l15;
                const int h = n >> 6, d = n & 63;
                const float bn = bias[n];
#pragma unroll
                for (int r = 0; r < 4; r++) {
                    const int mm = mbase + r;
                    const int b = mm >> 11, s = mm & 2047;
                    const int dsw = ((((d >> 3) ^ (s & 7)) & 7) << 3) | (d & 7);
                    Ko[(((size_t)(b * 16 + h) * 2048 + s) * 64) + dsw] =
                        f2bf(acc[i][j][r] + bn);
                }
            }
        }
    } else {
        // V^T: [B,H,dh,S] with s-chunk swizzle by (d&7); 4 consecutive s packed
#pragma unroll
        for (int i = 0; i < 4; i++) {
            const int mbase = m0 + wm + i * 16 + quad * 4;
            const int b = mbase >> 11, s0 = mbase & 2047;
#pragma unroll
            for (int j = 0; j < 4; j++) {
                const int n = n0 + wn + j * 16 + l15;
                const int h = n >> 6, d = n & 63;
                const float bn = bias[n];
                ushort4 v4;
                v4.x = f2bf(acc[i][j][0] + bn);
                v4.y = f2bf(acc[i][j][1] + bn);
                v4.z = f2bf(acc[i][j][2] + bn);
                v4.w = f2bf(acc[i][j][3] + bn);
                const int cs  = (s0 & 63) >> 3;
                const int ssw = (s0 & ~63) | (((cs ^ (d & 7)) & 7) << 3) | (s0 & 7);
                *reinterpret_cast<ushort4*>(
                    Vto + ((size_t)(b * 16 + h) * 64 + d) * 2048 + ssw) = v4;
            }
        }
    }
}

// ---------------------------------------------------------------------------
// Kernel 4: MFMA flash attention, max-free softmax, in-register P.
// 1 block = (b,h,128 q-rows), 8 waves; wave w owns q-rows [16w,16w+16).
// KVBLK=128 as 2x64 half-tiles per barrier: each half uses the verified
// 64x64 LDS layout + compute body; 16 iterations, barriers halved.
// Swapped QK^T -> in-register P; cvt_pk + permlane redistribution.
// Flat grid 512, XCD-bijective (K/V L2-resident). (R25 exact.)
// ---------------------------------------------------------------------------
__global__ __launch_bounds__(512) void attn3(
    const unsigned short* __restrict__ Qg,
    const unsigned short* __restrict__ Kg,
    const unsigned short* __restrict__ Vtg,
    float* __restrict__ out)
{
    __shared__ unsigned short Ks[2][2][64][64];   // [buf][half][kk][d] swizzled
    __shared__ unsigned short Vs[2][2][64][64];   // [buf][half][d][kk] swizzled

    const int tid  = threadIdx.x;
    const int lane = tid & 63;
    const int w    = tid >> 6;        // 0..7
    const int l15  = lane & 15;
    const int quad = lane >> 4;

    // XCD-bijective decode: lin = (bh&7) + 8*qb + 128*(bh>>3)
    const int lin = blockIdx.x;               // 0..511
    const int qb  = (lin >> 3) & 15;
    const int bh  = (lin & 7) | ((lin >> 7) << 3);
    const int q0  = qb * 128;
    const size_t base = (size_t)bh * 2048 * 64;
    const unsigned short* Qh  = Qg  + base;
    const unsigned short* Kh  = Kg  + base;
    const unsigned short* Vth = Vtg + base;
    const int b = bh >> 4;
    const int h = bh & 15;

    const int drow = lane >> 3;       // 0..7
    const int dcol = (lane & 7) * 8;  // 0..56

    bf16x8 qf[2];
#pragma unroll
    for (int ks = 0; ks < 2; ks++)
        qf[ks] = *reinterpret_cast<const bf16x8*>(
            Qh + (size_t)(q0 + w * 16 + l15) * 64 + ks * 32 + quad * 8);

    f32x4 o[4];
#pragma unroll
    for (int t = 0; t < 4; t++) o[t] = (f32x4){0.f, 0.f, 0.f, 0.f};
    float rsum = 0.f;   // per-lane: q = w*16 + l15

    // swizzled chunk columns for frag reads (row&7 == l15&7 for 16-row tiles)
    const int c0 = (((quad + 0) ^ (l15 & 7)) & 7) * 8;
    const int c1 = (((quad + 4) ^ (l15 & 7)) & 7) * 8;

    // prologue: stage tile 0, both halves (each wave: 8 K-rows, 8 V-rows per half)
#pragma unroll
    for (int hh = 0; hh < 2; hh++) {
        gload_lds16(Kh  + (size_t)(hh * 64 + w * 8 + drow) * 64 + dcol,
                    &Ks[0][hh][w * 8][0]);
        gload_lds16(Vth + (size_t)(w * 8 + drow) * 2048 + hh * 64 + dcol,
                    &Vs[0][hh][w * 8][0]);
    }
    __syncthreads();

    int cur = 0;
    for (int kt = 0; kt < 16; kt++) {
        // prefetch next 128-k tile (both halves) into the other buffer
        if (kt < 15) {
            const int kn = kt + 1;
#pragma unroll
            for (int hh = 0; hh < 2; hh++) {
                gload_lds16(Kh  + (size_t)(kn * 128 + hh * 64 + w * 8 + drow) * 64 + dcol,
                            &Ks[cur ^ 1][hh][w * 8][0]);
                gload_lds16(Vth + (size_t)(w * 8 + drow) * 2048 + kn * 128 + hh * 64 + dcol,
                            &Vs[cur ^ 1][hh][w * 8][0]);
            }
        }

#pragma unroll
        for (int hh = 0; hh < 2; hh++) {
            const unsigned short (*Kc)[64] = Ks[cur][hh];
            const unsigned short (*Vc)[64] = Vs[cur][hh];

            // S^T = K Q^T (swapped operands; scale+ln2 folded into Q).
            unsigned int D[4][2];
#pragma unroll
            for (int t = 0; t < 4; t++) {
                f32x4 sc = (f32x4){0.f, 0.f, 0.f, 0.f};
                bf16x8 kf0 = *reinterpret_cast<const bf16x8*>(&Kc[t * 16 + l15][c0]);
                bf16x8 kf1 = *reinterpret_cast<const bf16x8*>(&Kc[t * 16 + l15][c1]);
                __builtin_amdgcn_s_setprio(1);
                sc = MFMA16(kf0, qf[0], sc);
                sc = MFMA16(kf1, qf[1], sc);
                __builtin_amdgcn_s_setprio(0);
                const float p0 = EXP2(sc[0]);
                const float p1 = EXP2(sc[1]);
                const float p2 = EXP2(sc[2]);
                const float p3 = EXP2(sc[3]);
                rsum += (p0 + p1) + (p2 + p3);
                D[t][0] = pack2(p0, p1);
                D[t][1] = pack2(p2, p3);
            }

            // redistribute to PV A-fragment layout via permlane swaps
            bf16x8 pf[2];
#pragma unroll
            for (int ks = 0; ks < 2; ks++) {
                unsigned int x0 = D[2 * ks][0], y0 = D[2 * ks + 1][0];
                unsigned int x1 = D[2 * ks][1], y1 = D[2 * ks + 1][1];
                asm("v_permlane32_swap_b32 %0, %1" : "+v"(x0), "+v"(y0));
                asm("v_permlane16_swap_b32 %0, %1" : "+v"(x0), "+v"(y0));
                asm("v_permlane32_swap_b32 %0, %1" : "+v"(x1), "+v"(y1));
                asm("v_permlane16_swap_b32 %0, %1" : "+v"(x1), "+v"(y1));
                int4v pv_;
                pv_.x = (int)x0; pv_.y = (int)x1; pv_.z = (int)y0; pv_.w = (int)y1;
                pf[ks] = *reinterpret_cast<bf16x8*>(&pv_);
            }

#pragma unroll
            for (int t = 0; t < 4; t++) {
                bf16x8 vf0 = *reinterpret_cast<const bf16x8*>(&Vc[t * 16 + l15][c0]);
                bf16x8 vf1 = *reinterpret_cast<const bf16x8*>(&Vc[t * 16 + l15][c1]);
                __builtin_amdgcn_s_setprio(1);
                o[t] = MFMA16(pf[0], vf0, o[t]);
                o[t] = MFMA16(pf[1], vf1, o[t]);
                __builtin_amdgcn_s_setprio(0);
            }
        }

        __syncthreads();   // drains next tile's DMA + guards buffer reuse
        cur ^= 1;
    }

    // rsum total for q=w*16+l15: sum the 4 quads' partials
    rsum += __shfl_xor(rsum, 16, 64);
    rsum += __shfl_xor(rsum, 32, 64);
    float rinv[4];
#pragma unroll
    for (int r = 0; r < 4; r++)
        rinv[r] = 1.0f / __shfl(rsum, quad * 4 + r, 64);

    // epilogue: out[b][q][h*64+d], fp32
#pragma unroll
    for (int t = 0; t < 4; t++) {
#pragma unroll
        for (int r = 0; r < 4; r++) {
            const int q = q0 + w * 16 + quad * 4 + r;
            const size_t oidx = (((size_t)b * 2048 + q) * 16 + h) * 64 + t * 16 + l15;
            out[oidx] = o[t][r] * rinv[r];
        }
    }
}

// ---------------------------------------------------------------------------
__global__ void fill_sentinel(float* out, int n, float pat) {
    int i = blockIdx.x * blockDim.x + threadIdx.x;
    if (i < n) out[i] = pat;
}

// ---------------------------------------------------------------------------
extern "C" void kernel_launch(void* const* d_in, const int* in_sizes, int n_in,
                              void* d_out, int out_size, void* d_ws, size_t ws_size,
                              hipStream_t stream) {
    const size_t n_hs  = (size_t)4096 * 1024;
    const size_t n_w   = (size_t)1024 * 1024;
    const size_t n_qkv = n_hs;
    const size_t need = (n_hs + 3 * n_w + 3 * n_qkv) * sizeof(unsigned short);

    bool order_ok = (n_in == 7) &&
        in_sizes[0] == 4194304 &&
        in_sizes[1] == 1048576 && in_sizes[2] == 1024 &&
        in_sizes[3] == 1048576 && in_sizes[4] == 1024 &&
        in_sizes[5] == 1048576 && in_sizes[6] == 1024;
    if (!order_ok || out_size != 4194304) {
        fill_sentinel<<<(out_size + 255) / 256, 256, 0, stream>>>(
            (float*)d_out, out_size, 4.0f);
        return;
    }
    if (ws_size < need) {
        fill_sentinel<<<(out_size + 255) / 256, 256, 0, stream>>>(
            (float*)d_out, out_size, 2.0f);
        return;
    }

    const float* hs = (const float*)d_in[0];
    const float* Wq = (const float*)d_in[1];
    const float* bq = (const float*)d_in[2];
    const float* Wk = (const float*)d_in[3];
    const float* bk = (const float*)d_in[4];
    const float* Wv = (const float*)d_in[5];
    const float* bv = (const float*)d_in[6];

    unsigned short* hsb = (unsigned short*)d_ws;
    unsigned short* Wt  = hsb + n_hs;
    unsigned short* Q   = Wt + 3 * n_w;
    unsigned short* K   = Q + n_qkv;
    unsigned short* Vt  = K + n_qkv;

    prep<<<2816, 256, 0, stream>>>(hs, Wq, Wk, Wv, hsb, Wt);

    qkv_gemm_dma<<<dim3(768), dim3(256), 0, stream>>>(hsb, Wt, bq, bk, bv, Q, K, Vt);

    attn3<<<dim3(512), dim3(512), 0, stream>>>(Q, K, Vt, (float*)d_out);
}